// Round 4
// baseline (705.454 us; speedup 1.0000x reference)
//
#include <hip/hip_runtime.h>

#define D 64
#define BSH 5   // 32 nodes per bucket

// Per-bucket edge histogram for both directions.
__global__ void bucket_hist(const int* __restrict__ es, const int* __restrict__ ed,
                            int* __restrict__ bcnt_d, int* __restrict__ bcnt_s, int E) {
    int e = blockIdx.x * blockDim.x + threadIdx.x;
    if (e >= E) return;
    atomicAdd(&bcnt_d[ed[e] >> BSH], 1);
    atomicAdd(&bcnt_s[es[e] >> BSH], 1);
}

// Single-block exclusive scan (n <= ~8192). Writes base[0..n] (base[n]=total) and a copy to bpos.
__global__ void bucket_scan(const int* __restrict__ cnt, int* __restrict__ base,
                            int* __restrict__ bpos, int n) {
    const int T = 256;
    int t = threadIdx.x;
    int C = (n + T - 1) / T;
    int lo = t * C, hi = min(lo + C, n);
    int s = 0;
    for (int i = lo; i < hi; ++i) s += cnt[i];
    __shared__ int sh[T];
    sh[t] = s;
    __syncthreads();
    for (int off = 1; off < T; off <<= 1) {
        int x = (t >= off) ? sh[t - off] : 0;
        __syncthreads();
        sh[t] += x;
        __syncthreads();
    }
    int a = sh[t] - s;  // exclusive prefix of this thread's chunk
    for (int i = lo; i < hi; ++i) { int c = cnt[i]; base[i] = a; bpos[i] = a; a += c; }
    if (t == T - 1) base[n] = sh[T - 1];
}

// Scatter (other,node) pairs into per-bucket contiguous regions (both directions).
__global__ void partition(const int* __restrict__ es, const int* __restrict__ ed,
                          int2* __restrict__ pd, int2* __restrict__ ps,
                          int* __restrict__ bpos_d, int* __restrict__ bpos_s, int E) {
    int e = blockIdx.x * blockDim.x + threadIdx.x;
    if (e >= E) return;
    int s = es[e], d = ed[e];
    pd[atomicAdd(&bpos_d[d >> BSH], 1)] = make_int2(s, d);
    ps[atomicAdd(&bpos_s[s >> BSH], 1)] = make_int2(d, s);
}

// One block per bucket: per-node count (LDS) -> local scan -> row offsets + grouped vals.
__global__ void finalize(const int2* __restrict__ pairs, const int* __restrict__ bbase,
                         int* __restrict__ ro, int* __restrict__ vals, int n, int nb) {
    int b = blockIdx.x;
    int t = threadIdx.x;
    if (b >= nb) return;
    int beg = bbase[b], end = bbase[b + 1];
    __shared__ int cnt[32], pos[32], sc[33];
    if (t < 32) { cnt[t] = 0; pos[t] = 0; }
    __syncthreads();
    for (int j = beg + t; j < end; j += blockDim.x)
        atomicAdd(&cnt[pairs[j].y & 31], 1);
    __syncthreads();
    if (t == 0) { int a = 0; for (int i = 0; i < 32; ++i) { sc[i] = a; a += cnt[i]; } sc[32] = a; }
    __syncthreads();
    int node0 = b << BSH;
    if (t < 32 && node0 + t < n) ro[node0 + t] = beg + sc[t];
    if (b == nb - 1 && t == 0) ro[n] = end;
    for (int j = beg + t; j < end; j += blockDim.x) {
        int2 pr = pairs[j];
        int ln = pr.y & 31;
        int p = atomicAdd(&pos[ln], 1);
        vals[beg + sc[ln] + p] = pr.x;
    }
}

// One wave per dst node: gather-sum feat_src rows, then fused attention + degree norm.
__global__ void fwd_gather_attn(const float* __restrict__ feat_src,
                                const float* __restrict__ pf,
                                const int* __restrict__ ro, const int* __restrict__ vals,
                                float* __restrict__ rst, int n_dst) {
    int n = blockIdx.x * 4 + (threadIdx.x >> 6);
    int lane = threadIdx.x & 63;
    if (n >= n_dst) return;
    int beg = ro[n], end = ro[n + 1];
    float acc = 0.f;
    int j = beg;
    for (; j + 4 <= end; j += 4) {
        int s0 = vals[j], s1 = vals[j + 1], s2 = vals[j + 2], s3 = vals[j + 3];
        acc += feat_src[(size_t)s0 * D + lane];
        acc += feat_src[(size_t)s1 * D + lane];
        acc += feat_src[(size_t)s2 * D + lane];
        acc += feat_src[(size_t)s3 * D + lane];
    }
    for (; j < end; ++j) acc += feat_src[(size_t)vals[j] * D + lane];

    const float* p = pf + (size_t)n * 4 * D + lane;
    float p0 = p[0], p1 = p[D], p2 = p[2 * D], p3 = p[3 * D];
    float s0 = acc * p0, s1 = acc * p1, s2 = acc * p2, s3 = acc * p3;
    #pragma unroll
    for (int off = 32; off >= 1; off >>= 1) {
        s0 += __shfl_xor(s0, off);
        s1 += __shfl_xor(s1, off);
        s2 += __shfl_xor(s2, off);
        s3 += __shfl_xor(s3, off);
    }
    s0 *= 0.125f; s1 *= 0.125f; s2 *= 0.125f; s3 *= 0.125f;
    float m = fmaxf(fmaxf(s0, s1), fmaxf(s2, s3));
    float e0 = expf(s0 - m), e1 = expf(s1 - m), e2 = expf(s2 - m), e3 = expf(s3 - m);
    float inv = 1.0f / (e0 + e1 + e2 + e3);
    float patt = (e0 * p0 + e1 * p1 + e2 * p2 + e3 * p3) * inv;
    float out = (acc + 0.1f * tanhf(patt)) / fmaxf((float)(end - beg), 1.0f);
    rst[(size_t)n * D + lane] = out;
}

// One wave per src node: gather-sum rst rows, fused out-degree norm.
__global__ void bwd_gather(const float* __restrict__ rst,
                           const int* __restrict__ ro, const int* __restrict__ vals,
                           float* __restrict__ bsrc, int n_src) {
    int n = blockIdx.x * 4 + (threadIdx.x >> 6);
    int lane = threadIdx.x & 63;
    if (n >= n_src) return;
    int beg = ro[n], end = ro[n + 1];
    float acc = 0.f;
    int j = beg;
    for (; j + 4 <= end; j += 4) {
        int d0 = vals[j], d1 = vals[j + 1], d2 = vals[j + 2], d3 = vals[j + 3];
        acc += rst[(size_t)d0 * D + lane];
        acc += rst[(size_t)d1 * D + lane];
        acc += rst[(size_t)d2 * D + lane];
        acc += rst[(size_t)d3 * D + lane];
    }
    for (; j < end; ++j) acc += rst[(size_t)vals[j] * D + lane];
    bsrc[(size_t)n * D + lane] = acc / fmaxf((float)(end - beg), 1.0f);
}

extern "C" void kernel_launch(void* const* d_in, const int* in_sizes, int n_in,
                              void* d_out, int out_size, void* d_ws, size_t ws_size,
                              hipStream_t stream) {
    const float* feat_src = (const float*)d_in[0];
    const float* pf       = (const float*)d_in[2];
    const int*   edge_src = (const int*)d_in[3];
    const int*   edge_dst = (const int*)d_in[4];

    int n_src = in_sizes[0] / D;
    int n_dst = in_sizes[1] / D;
    int E     = in_sizes[3];

    int nb_d = (n_dst + 31) >> BSH;
    int nb_s = (n_src + 31) >> BSH;

    float* bsrc = (float*)d_out;                      // [n_src, D] — written LAST
    float* rst  = (float*)d_out + (size_t)n_src * D;  // [n_dst, D]

    // Pair arrays live in the bsrc region of d_out (only overwritten by the final kernel).
    int2* pairs_d = (int2*)d_out;        // E pairs (10 MB)
    int2* pairs_s = pairs_d + E;         // E pairs (10 MB)  — total 20 MB < n_src*D*4 = 51.2 MB

    // workspace (ints), ~11.3 MB
    int* w = (int*)d_ws;
    int* bcnt_d  = w;  w += nb_d;
    int* bcnt_s  = w;  w += nb_s;        // contiguous with bcnt_d -> one memset
    int* bbase_d = w;  w += nb_d + 1;
    int* bbase_s = w;  w += nb_s + 1;
    int* bpos_d  = w;  w += nb_d;
    int* bpos_s  = w;  w += nb_s;
    int* ro_d    = w;  w += n_dst + 1;
    int* ro_s    = w;  w += n_src + 1;
    int* vals_d  = w;  w += E;
    int* vals_s  = w;  w += E;

    hipMemsetAsync(bcnt_d, 0, (size_t)(nb_d + nb_s) * sizeof(int), stream);

    bucket_hist<<<(E + 255) / 256, 256, 0, stream>>>(edge_src, edge_dst, bcnt_d, bcnt_s, E);
    bucket_scan<<<1, 256, 0, stream>>>(bcnt_d, bbase_d, bpos_d, nb_d);
    bucket_scan<<<1, 256, 0, stream>>>(bcnt_s, bbase_s, bpos_s, nb_s);
    partition<<<(E + 255) / 256, 256, 0, stream>>>(edge_src, edge_dst, pairs_d, pairs_s,
                                                   bpos_d, bpos_s, E);
    finalize<<<nb_d, 256, 0, stream>>>(pairs_d, bbase_d, ro_d, vals_d, n_dst, nb_d);
    finalize<<<nb_s, 256, 0, stream>>>(pairs_s, bbase_s, ro_s, vals_s, n_src, nb_s);

    fwd_gather_attn<<<(n_dst + 3) / 4, 256, 0, stream>>>(feat_src, pf, ro_d, vals_d, rst, n_dst);
    bwd_gather<<<(n_src + 3) / 4, 256, 0, stream>>>(rst, ro_s, vals_s, bsrc, n_src);
}